// Round 10
// baseline (459.892 us; speedup 1.0000x reference)
//
#include <hip/hip_runtime.h>
#include <math.h>

#define HID 128
#define NEG_SLOPE 0.2f

// ---------------- edge dtype detection ----------------
// (Round-5 evidence: edges delivered as int32 here, but probe kept — it is
//  correct for both int32 and int64<2^31 deliveries and costs ~3us.)
__global__ void detect64_kernel(const int* __restrict__ e32, int* __restrict__ is64,
                                long long nwords32) {
    int lane = threadIdx.x & 63;
    int nz = 0;
    #pragma unroll
    for (int q = 0; q < 8; ++q) {
        long long idx = 2LL * (lane * 8 + q) + 1;
        if (idx < nwords32) nz |= (e32[idx] != 0);
    }
    unsigned long long b = __ballot(nz);
    if (lane == 0) *is64 = (b == 0ULL) ? 1 : 0;
}

__device__ __forceinline__ int eload(const void* edges, int is64, long long i) {
    return is64 ? (int)((const long long*)edges)[i] : ((const int*)edges)[i];
}

// ---------------- CSR build ----------------

__global__ void zero_cnt_kernel(int* __restrict__ cnt, int n) {
    int i = blockIdx.x * blockDim.x + threadIdx.x;
    if (i < n) cnt[i] = 0;
}

__global__ void hist_kernel(const void* __restrict__ edges, const int* __restrict__ is64p,
                            int* __restrict__ cnt, int e) {
    int i = blockIdx.x * blockDim.x + threadIdx.x;
    if (i < e) {
        int is64 = *is64p;
        int d = eload(edges, is64, (long long)e + i);   // dst row
        atomicAdd(&cnt[d], 1);
    }
}

// hierarchical exclusive scan of cnt[0..n) -> off/cursor; off[n] = total
__global__ __launch_bounds__(256) void scan1_kernel(const int* __restrict__ cnt,
                                                    int* __restrict__ tmp,
                                                    int* __restrict__ partials, int n) {
    __shared__ int s[256];
    const int t = threadIdx.x;
    const int i0 = blockIdx.x * 1024 + t * 4;
    int v0 = (i0 + 0 < n) ? cnt[i0 + 0] : 0;
    int v1 = (i0 + 1 < n) ? cnt[i0 + 1] : 0;
    int v2 = (i0 + 2 < n) ? cnt[i0 + 2] : 0;
    int v3 = (i0 + 3 < n) ? cnt[i0 + 3] : 0;
    int sum = v0 + v1 + v2 + v3;
    s[t] = sum;
    __syncthreads();
    for (int d = 1; d < 256; d <<= 1) {
        int tt = (t >= d) ? s[t - d] : 0;
        __syncthreads();
        s[t] += tt;
        __syncthreads();
    }
    int run = s[t] - sum;
    if (t == 255) partials[blockIdx.x] = s[255];
    if (i0 + 0 < n) tmp[i0 + 0] = run; run += v0;
    if (i0 + 1 < n) tmp[i0 + 1] = run; run += v1;
    if (i0 + 2 < n) tmp[i0 + 2] = run; run += v2;
    if (i0 + 3 < n) tmp[i0 + 3] = run;
}

// scan2: one 64-lane wave scans (<=64) chunk partials in-place (exclusive).
__global__ void scan2_kernel(int* __restrict__ partials, int nchunks, int* __restrict__ off_n) {
    int lane = threadIdx.x;
    int orig = (lane < nchunks) ? partials[lane] : 0;
    int v = orig;
    for (int d = 1; d < 64; d <<= 1) {
        int t = __shfl_up(v, d);
        if (lane >= d) v += t;
    }
    if (lane < nchunks) partials[lane] = v - orig;
    if (lane == 63) *off_n = v;
}

__global__ void scan3_kernel(const int* __restrict__ tmp, const int* __restrict__ partials,
                             int* __restrict__ off, int* __restrict__ cursor, int n) {
    int i = blockIdx.x * blockDim.x + threadIdx.x;
    if (i < n) {
        int v = tmp[i] + partials[i >> 10];
        off[i] = v;
        cursor[i] = v;
    }
}

__global__ void scatter_kernel(const void* __restrict__ edges, const int* __restrict__ is64p,
                               int* __restrict__ cursor, int* __restrict__ esrc, int e) {
    int i = blockIdx.x * blockDim.x + threadIdx.x;
    if (i < e) {
        int is64 = *is64p;
        int s = eload(edges, is64, i);                   // src row
        int d = eload(edges, is64, (long long)e + i);    // dst row
        int p = atomicAdd(&cursor[d], 1);
        esrc[p] = s;
    }
}

// ---------------- dual GEMM: OL = X @ WL, OR = X @ WR ----------------
// Round-6 restructure (evidence: Occupancy 8.5%, VALUBusy 26%, barrier-
// serialized W staging). W is L1/L2-resident and wave-uniform per k ->
// read it from GLOBAL (L1 broadcast), no LDS staging, ZERO barriers in
// the K-loop. Only Xs in LDS (32KB -> 5 blocks/CU by LDS). VGPR capped
// via launch_bounds(256,3) -> 12 waves/CU (~37% occupancy).

__global__ __launch_bounds__(256, 3) void gemm_dual_kernel(const float* __restrict__ X,
                                                           const float* __restrict__ WL,
                                                           const float* __restrict__ WR,
                                                           float* __restrict__ OL,
                                                           float* __restrict__ ORp, int n) {
    __shared__ float Xs[64][128];
    const int tid = threadIdx.x;
    const int row0 = blockIdx.x * 64;

    // stage X tile (zero-pad OOB rows)
    #pragma unroll
    for (int i = tid * 4; i < 64 * 128; i += 256 * 4) {
        int r = i >> 7, c = i & 127;
        float4 v = make_float4(0.f, 0.f, 0.f, 0.f);
        if (row0 + r < n) v = *(const float4*)&X[(size_t)(row0 + r) * HID + c];
        *(float4*)&Xs[r][c] = v;
    }
    __syncthreads();   // the ONLY barrier

    const int tr = tid >> 5;   // 0..7 -> rows tr*8 .. tr*8+7
    const int tc = tid & 31;   // cols tc*4 .. tc*4+3
    const float* __restrict__ wlp = WL + tc * 4;
    const float* __restrict__ wrp = WR + tc * 4;
    float accL[8][4] = {};
    float accR[8][4] = {};

    #pragma unroll 2
    for (int k4 = 0; k4 < 128; k4 += 4) {
        float4 wl[4], wr[4];
        #pragma unroll
        for (int q = 0; q < 4; ++q) {
            wl[q] = *(const float4*)&wlp[(size_t)(k4 + q) * 128];
            wr[q] = *(const float4*)&wrp[(size_t)(k4 + q) * 128];
        }
        #pragma unroll
        for (int r = 0; r < 8; ++r) {
            float4 xv = *(const float4*)&Xs[tr * 8 + r][k4];   // 4 consecutive k
            accL[r][0] = fmaf(xv.x, wl[0].x, accL[r][0]);
            accL[r][1] = fmaf(xv.x, wl[0].y, accL[r][1]);
            accL[r][2] = fmaf(xv.x, wl[0].z, accL[r][2]);
            accL[r][3] = fmaf(xv.x, wl[0].w, accL[r][3]);
            accR[r][0] = fmaf(xv.x, wr[0].x, accR[r][0]);
            accR[r][1] = fmaf(xv.x, wr[0].y, accR[r][1]);
            accR[r][2] = fmaf(xv.x, wr[0].z, accR[r][2]);
            accR[r][3] = fmaf(xv.x, wr[0].w, accR[r][3]);

            accL[r][0] = fmaf(xv.y, wl[1].x, accL[r][0]);
            accL[r][1] = fmaf(xv.y, wl[1].y, accL[r][1]);
            accL[r][2] = fmaf(xv.y, wl[1].z, accL[r][2]);
            accL[r][3] = fmaf(xv.y, wl[1].w, accL[r][3]);
            accR[r][0] = fmaf(xv.y, wr[1].x, accR[r][0]);
            accR[r][1] = fmaf(xv.y, wr[1].y, accR[r][1]);
            accR[r][2] = fmaf(xv.y, wr[1].z, accR[r][2]);
            accR[r][3] = fmaf(xv.y, wr[1].w, accR[r][3]);

            accL[r][0] = fmaf(xv.z, wl[2].x, accL[r][0]);
            accL[r][1] = fmaf(xv.z, wl[2].y, accL[r][1]);
            accL[r][2] = fmaf(xv.z, wl[2].z, accL[r][2]);
            accL[r][3] = fmaf(xv.z, wl[2].w, accL[r][3]);
            accR[r][0] = fmaf(xv.z, wr[2].x, accR[r][0]);
            accR[r][1] = fmaf(xv.z, wr[2].y, accR[r][1]);
            accR[r][2] = fmaf(xv.z, wr[2].z, accR[r][2]);
            accR[r][3] = fmaf(xv.z, wr[2].w, accR[r][3]);

            accL[r][0] = fmaf(xv.w, wl[3].x, accL[r][0]);
            accL[r][1] = fmaf(xv.w, wl[3].y, accL[r][1]);
            accL[r][2] = fmaf(xv.w, wl[3].z, accL[r][2]);
            accL[r][3] = fmaf(xv.w, wl[3].w, accL[r][3]);
            accR[r][0] = fmaf(xv.w, wr[3].x, accR[r][0]);
            accR[r][1] = fmaf(xv.w, wr[3].y, accR[r][1]);
            accR[r][2] = fmaf(xv.w, wr[3].z, accR[r][2]);
            accR[r][3] = fmaf(xv.w, wr[3].w, accR[r][3]);
        }
    }

    #pragma unroll
    for (int r = 0; r < 8; ++r) {
        int row = row0 + tr * 8 + r;
        if (row < n) {
            *(float4*)&OL[(size_t)row * HID + tc * 4] =
                make_float4(accL[r][0], accL[r][1], accL[r][2], accL[r][3]);
            *(float4*)&ORp[(size_t)row * HID + tc * 4] =
                make_float4(accR[r][0], accR[r][1], accR[r][2], accR[r][3]);
        }
    }
}

// ---------------- fused GATv2 edge-softmax + aggregation ----------------
// One wave per destination node; lane l owns feature comps 2l,2l+1 (head l>>3).
// Online softmax; self-loop first; edge loop unrolled x4 (4 gathers in flight).

#define PROC(XLX, XLY)                                                         \
    {                                                                          \
        float t0 = (XLX) + xrv.x; t0 = (t0 > 0.f) ? t0 : NEG_SLOPE * t0;       \
        float t1 = (XLY) + xrv.y; t1 = (t1 > 0.f) ? t1 : NEG_SLOPE * t1;       \
        float p = t0 * attv.x + t1 * attv.y;                                   \
        p += __shfl_xor(p, 1);                                                 \
        p += __shfl_xor(p, 2);                                                 \
        p += __shfl_xor(p, 4);                                                 \
        float mnew = fmaxf(m, p);                                              \
        float scale = __expf(m - mnew);                                        \
        float w = __expf(p - mnew);                                            \
        den = den * scale + w;                                                 \
        acc0 = acc0 * scale + w * (XLX);                                       \
        acc1 = acc1 * scale + w * (XLY);                                       \
        m = mnew;                                                              \
    }

__global__ __launch_bounds__(256) void aggregate_kernel(const float* __restrict__ xl,
                                                        const float* __restrict__ xr,
                                                        const float* __restrict__ att,
                                                        const float* __restrict__ bias,
                                                        const int* __restrict__ off,
                                                        const int* __restrict__ esrc,
                                                        float* __restrict__ out,
                                                        int n, int do_relu) {
    int node = blockIdx.x * (blockDim.x >> 6) + (threadIdx.x >> 6);
    if (node >= n) return;
    const int lane = threadIdx.x & 63;

    const float2 xrv = ((const float2*)(xr + (size_t)node * HID))[lane];
    const float2 attv = ((const float2*)att)[lane];

    float m = -INFINITY, den = 0.f, acc0 = 0.f, acc1 = 0.f;
    const int start = off[node], end = off[node + 1];

    // self-loop (softmax is order-invariant)
    {
        float2 xlv = ((const float2*)(xl + (size_t)node * HID))[lane];
        PROC(xlv.x, xlv.y);
    }
    int j = start;
    for (; j + 3 < end; j += 4) {
        int s0 = esrc[j];
        int s1 = esrc[j + 1];
        int s2 = esrc[j + 2];
        int s3 = esrc[j + 3];
        float2 a = ((const float2*)(xl + (size_t)s0 * HID))[lane];
        float2 b = ((const float2*)(xl + (size_t)s1 * HID))[lane];
        float2 c = ((const float2*)(xl + (size_t)s2 * HID))[lane];
        float2 d = ((const float2*)(xl + (size_t)s3 * HID))[lane];
        PROC(a.x, a.y);
        PROC(b.x, b.y);
        PROC(c.x, c.y);
        PROC(d.x, d.y);
    }
    for (; j < end; ++j) {
        int s0 = esrc[j];
        float2 a = ((const float2*)(xl + (size_t)s0 * HID))[lane];
        PROC(a.x, a.y);
    }

    const float2 bv = ((const float2*)bias)[lane];
    float inv = 1.0f / den;
    float o0 = acc0 * inv + bv.x;
    float o1 = acc1 * inv + bv.y;
    if (do_relu) { o0 = fmaxf(o0, 0.f); o1 = fmaxf(o1, 0.f); }
    ((float2*)(out + (size_t)node * HID))[lane] = make_float2(o0, o1);
}

// ---------------- launch ----------------

extern "C" void kernel_launch(void* const* d_in, const int* in_sizes, int n_in,
                              void* d_out, int out_size, void* d_ws, size_t ws_size,
                              hipStream_t stream) {
    const float* x     = (const float*)d_in[0];
    const void*  edges = d_in[1];
    const float* Wl1   = (const float*)d_in[2];
    const float* Wr1   = (const float*)d_in[3];
    const float* att1  = (const float*)d_in[4];
    const float* b1    = (const float*)d_in[5];
    const float* Wl2   = (const float*)d_in[6];
    const float* Wr2   = (const float*)d_in[7];
    const float* att2  = (const float*)d_in[8];
    const float* b2    = (const float*)d_in[9];
    float* out = (float*)d_out;

    const int n = in_sizes[0] / HID;
    const int e = in_sizes[1] / 2;   // element count per the harness contract

    char* ws = (char*)d_ws;
    size_t o = 0;
    auto alloc = [&](size_t bytes) -> void* {
        void* p = ws + o;
        o = (o + bytes + 255) & ~(size_t)255;
        return p;
    };
    int* cnt      = (int*)alloc((size_t)n * 4);
    int* off      = (int*)alloc((size_t)(n + 1) * 4);
    int* cursor   = (int*)alloc((size_t)n * 4);
    int* esrc     = (int*)alloc((size_t)e * 4);
    int* tmp      = (int*)alloc((size_t)n * 4);
    int* partials = (int*)alloc(64 * 4);
    int* is64     = (int*)alloc(256);
    float* A      = (float*)alloc((size_t)n * HID * 4);   // xl
    float* B      = (float*)alloc((size_t)n * HID * 4);   // xr
    float* H      = out;                                   // layer-1 output lives in d_out

    const int nchunks = (n + 1023) / 1024;   // 49 for n=50000 (<=64 required)

    // CSR by destination (shared by both layers)
    detect64_kernel<<<1, 64, 0, stream>>>((const int*)edges, is64, 2LL * e);
    zero_cnt_kernel<<<(n + 255) / 256, 256, 0, stream>>>(cnt, n);
    hist_kernel<<<(e + 255) / 256, 256, 0, stream>>>(edges, is64, cnt, e);
    scan1_kernel<<<nchunks, 256, 0, stream>>>(cnt, tmp, partials, n);
    scan2_kernel<<<1, 64, 0, stream>>>(partials, nchunks, off + n);
    scan3_kernel<<<(n + 255) / 256, 256, 0, stream>>>(tmp, partials, off, cursor, n);
    scatter_kernel<<<(e + 255) / 256, 256, 0, stream>>>(edges, is64, cursor, esrc, e);

    const int gblocks = (n + 63) / 64;

    // layer 1
    gemm_dual_kernel<<<gblocks, 256, 0, stream>>>(x, Wl1, Wr1, A, B, n);
    aggregate_kernel<<<(n + 3) / 4, 256, 0, stream>>>(A, B, att1, b1, off, esrc, H, n, 1);

    // layer 2
    gemm_dual_kernel<<<gblocks, 256, 0, stream>>>(H, Wl2, Wr2, A, B, n);
    aggregate_kernel<<<(n + 3) / 4, 256, 0, stream>>>(A, B, att2, b2, off, esrc, out, n, 0);
}

// Round 15
// 351.637 us; speedup vs baseline: 1.3079x; 1.3079x over previous
//
#include <hip/hip_runtime.h>
#include <math.h>

#define HID 128
#define NEG_SLOPE 0.2f

typedef __attribute__((ext_vector_type(8))) short bf16x8;   // 8 bf16 = 4 VGPRs
typedef __attribute__((ext_vector_type(4))) float f32x4;

__device__ __forceinline__ unsigned short bf16_rne(float f) {
    unsigned int u = __float_as_uint(f);
    u = u + 0x7fffu + ((u >> 16) & 1u);
    return (unsigned short)(u >> 16);
}
__device__ __forceinline__ float bf16_tof(unsigned short h) {
    return __uint_as_float(((unsigned int)h) << 16);
}

// ---------------- edge dtype detection (kept; ~3us, robust to int32/int64) ----
__global__ void detect64_kernel(const int* __restrict__ e32, int* __restrict__ is64,
                                long long nwords32) {
    int lane = threadIdx.x & 63;
    int nz = 0;
    #pragma unroll
    for (int q = 0; q < 8; ++q) {
        long long idx = 2LL * (lane * 8 + q) + 1;
        if (idx < nwords32) nz |= (e32[idx] != 0);
    }
    unsigned long long b = __ballot(nz);
    if (lane == 0) *is64 = (b == 0ULL) ? 1 : 0;
}

__device__ __forceinline__ int eload(const void* edges, int is64, long long i) {
    return is64 ? (int)((const long long*)edges)[i] : ((const int*)edges)[i];
}

// ---------------- CSR build (unchanged) ----------------

__global__ void zero_cnt_kernel(int* __restrict__ cnt, int n) {
    int i = blockIdx.x * blockDim.x + threadIdx.x;
    if (i < n) cnt[i] = 0;
}

__global__ void hist_kernel(const void* __restrict__ edges, const int* __restrict__ is64p,
                            int* __restrict__ cnt, int e) {
    int i = blockIdx.x * blockDim.x + threadIdx.x;
    if (i < e) {
        int is64 = *is64p;
        int d = eload(edges, is64, (long long)e + i);
        atomicAdd(&cnt[d], 1);
    }
}

__global__ __launch_bounds__(256) void scan1_kernel(const int* __restrict__ cnt,
                                                    int* __restrict__ tmp,
                                                    int* __restrict__ partials, int n) {
    __shared__ int s[256];
    const int t = threadIdx.x;
    const int i0 = blockIdx.x * 1024 + t * 4;
    int v0 = (i0 + 0 < n) ? cnt[i0 + 0] : 0;
    int v1 = (i0 + 1 < n) ? cnt[i0 + 1] : 0;
    int v2 = (i0 + 2 < n) ? cnt[i0 + 2] : 0;
    int v3 = (i0 + 3 < n) ? cnt[i0 + 3] : 0;
    int sum = v0 + v1 + v2 + v3;
    s[t] = sum;
    __syncthreads();
    for (int d = 1; d < 256; d <<= 1) {
        int tt = (t >= d) ? s[t - d] : 0;
        __syncthreads();
        s[t] += tt;
        __syncthreads();
    }
    int run = s[t] - sum;
    if (t == 255) partials[blockIdx.x] = s[255];
    if (i0 + 0 < n) tmp[i0 + 0] = run; run += v0;
    if (i0 + 1 < n) tmp[i0 + 1] = run; run += v1;
    if (i0 + 2 < n) tmp[i0 + 2] = run; run += v2;
    if (i0 + 3 < n) tmp[i0 + 3] = run;
}

__global__ void scan2_kernel(int* __restrict__ partials, int nchunks, int* __restrict__ off_n) {
    int lane = threadIdx.x;
    int orig = (lane < nchunks) ? partials[lane] : 0;
    int v = orig;
    for (int d = 1; d < 64; d <<= 1) {
        int t = __shfl_up(v, d);
        if (lane >= d) v += t;
    }
    if (lane < nchunks) partials[lane] = v - orig;
    if (lane == 63) *off_n = v;
}

__global__ void scan3_kernel(const int* __restrict__ tmp, const int* __restrict__ partials,
                             int* __restrict__ off, int* __restrict__ cursor, int n) {
    int i = blockIdx.x * blockDim.x + threadIdx.x;
    if (i < n) {
        int v = tmp[i] + partials[i >> 10];
        off[i] = v;
        cursor[i] = v;
    }
}

__global__ void scatter_kernel(const void* __restrict__ edges, const int* __restrict__ is64p,
                               int* __restrict__ cursor, int* __restrict__ esrc, int e) {
    int i = blockIdx.x * blockDim.x + threadIdx.x;
    if (i < e) {
        int is64 = *is64p;
        int s = eload(edges, is64, i);
        int d = eload(edges, is64, (long long)e + i);
        int p = atomicAdd(&cursor[d], 1);
        esrc[p] = s;
    }
}

// ---------------- bf16 hi/lo conversions ----------------
// X (fp32 [n][128]) -> Xhi,Xlo (bf16 [n][128]); x = hi + lo + O(2^-18 |x|)
__global__ void convert_x_kernel(const float* __restrict__ X, ushort* __restrict__ hi,
                                 ushort* __restrict__ lo, int total4) {
    int i = blockIdx.x * blockDim.x + threadIdx.x;
    if (i >= total4) return;
    float4 v = ((const float4*)X)[i];
    ushort4 h, l;
    h.x = bf16_rne(v.x); l.x = bf16_rne(v.x - bf16_tof(h.x));
    h.y = bf16_rne(v.y); l.y = bf16_rne(v.y - bf16_tof(h.y));
    h.z = bf16_rne(v.z); l.z = bf16_rne(v.z - bf16_tof(h.z));
    h.w = bf16_rne(v.w); l.w = bf16_rne(v.w - bf16_tof(h.w));
    ((ushort4*)hi)[i] = h;
    ((ushort4*)lo)[i] = l;
}

// [Wl|Wr] (fp32 [k=128][col=128] each) -> transposed Wt[col=256][k=128] hi/lo bf16
__global__ void convert_w_kernel(const float* __restrict__ Wl, const float* __restrict__ Wr,
                                 ushort* __restrict__ whi, ushort* __restrict__ wlo) {
    int t = blockIdx.x * blockDim.x + threadIdx.x;   // 0..32767
    int col = t >> 7, k = t & 127;
    float v = (col < 128) ? Wl[k * 128 + col] : Wr[k * 128 + (col - 128)];
    ushort h = bf16_rne(v);
    whi[t] = h;
    wlo[t] = bf16_rne(v - bf16_tof(h));
}

// ---------------- MFMA dual GEMM: [OL|OR] = X @ [WL|WR] ----------------
// 16x16x32 bf16 MFMA, split-bf16 3-term (hi*hi + hi*lo + lo*hi) == fp32-grade.
// Block = 64 rows x 256 cols, 4 waves; wave w owns 64 cols. Per wave:
// acc 4x4 tiles (64 VGPR), K-loop 4 steps of 32. A/B frags loaded straight
// from global (A: 16B contiguous per lane; B from pre-transposed Wt[col][k]).
// Verified m89 layout: A[m=l&15][k=(l>>4)*8+j], B[n=l&15][k=...],
// D[row=(l>>4)*4+j][col=l&15].
__global__ __launch_bounds__(256) void gemm_mfma_kernel(
        const ushort* __restrict__ Xhi, const ushort* __restrict__ Xlo,
        const ushort* __restrict__ Whi, const ushort* __restrict__ Wlo,
        float* __restrict__ OL, float* __restrict__ ORp, int n) {
    const int lane = threadIdx.x & 63;
    const int wv = threadIdx.x >> 6;
    const int row0 = blockIdx.x * 64;
    const int m16 = lane & 15;
    const int koff = (lane >> 4) * 8;
    const int colb = wv * 64;

    f32x4 acc[4][4];
    #pragma unroll
    for (int i = 0; i < 4; ++i)
        #pragma unroll
        for (int j = 0; j < 4; ++j)
            acc[i][j] = (f32x4){0.f, 0.f, 0.f, 0.f};

    int arow[4];
    #pragma unroll
    for (int rt = 0; rt < 4; ++rt) {
        int r = row0 + rt * 16 + m16;
        arow[rt] = (r < n) ? r : (n - 1);   // clamp tail; stores are guarded
    }

    #pragma unroll
    for (int ks = 0; ks < 4; ++ks) {
        const int k0 = ks * 32 + koff;
        bf16x8 bh[4], bl[4], ah[4], al[4];
        #pragma unroll
        for (int ct = 0; ct < 4; ++ct) {
            int c = colb + ct * 16 + m16;
            bh[ct] = *(const bf16x8*)&Whi[c * 128 + k0];
            bl[ct] = *(const bf16x8*)&Wlo[c * 128 + k0];
        }
        #pragma unroll
        for (int rt = 0; rt < 4; ++rt) {
            ah[rt] = *(const bf16x8*)&Xhi[(size_t)arow[rt] * 128 + k0];
            al[rt] = *(const bf16x8*)&Xlo[(size_t)arow[rt] * 128 + k0];
        }
        #pragma unroll
        for (int rt = 0; rt < 4; ++rt)
            #pragma unroll
            for (int ct = 0; ct < 4; ++ct) {
                acc[rt][ct] = __builtin_amdgcn_mfma_f32_16x16x32_bf16(ah[rt], bh[ct], acc[rt][ct], 0, 0, 0);
                acc[rt][ct] = __builtin_amdgcn_mfma_f32_16x16x32_bf16(ah[rt], bl[ct], acc[rt][ct], 0, 0, 0);
                acc[rt][ct] = __builtin_amdgcn_mfma_f32_16x16x32_bf16(al[rt], bh[ct], acc[rt][ct], 0, 0, 0);
            }
    }

    float* __restrict__ O = (wv < 2) ? OL : ORp;
    const int cb = (wv < 2) ? colb : (colb - 128);
    const int rbase = (lane >> 4) * 4;
    #pragma unroll
    for (int rt = 0; rt < 4; ++rt) {
        #pragma unroll
        for (int j = 0; j < 4; ++j) {
            int row = row0 + rt * 16 + rbase + j;
            if (row < n) {
                #pragma unroll
                for (int ct = 0; ct < 4; ++ct)
                    O[(size_t)row * HID + cb + ct * 16 + m16] = acc[rt][ct][j];
            }
        }
    }
}

// ---------------- fused GATv2 edge-softmax + aggregation ----------------
// One wave per destination node; lane l owns comps 2l,2l+1 (head l>>3).
// Online softmax; self-loop first; edge loop unrolled x4.
// Epilogue: if hhi != null, write bf16 hi/lo (for next layer's MFMA GEMM);
// else write fp32 out.

#define PROC(XLX, XLY)                                                         \
    {                                                                          \
        float t0 = (XLX) + xrv.x; t0 = (t0 > 0.f) ? t0 : NEG_SLOPE * t0;       \
        float t1 = (XLY) + xrv.y; t1 = (t1 > 0.f) ? t1 : NEG_SLOPE * t1;       \
        float p = t0 * attv.x + t1 * attv.y;                                   \
        p += __shfl_xor(p, 1);                                                 \
        p += __shfl_xor(p, 2);                                                 \
        p += __shfl_xor(p, 4);                                                 \
        float mnew = fmaxf(m, p);                                              \
        float scale = __expf(m - mnew);                                        \
        float w = __expf(p - mnew);                                            \
        den = den * scale + w;                                                 \
        acc0 = acc0 * scale + w * (XLX);                                       \
        acc1 = acc1 * scale + w * (XLY);                                       \
        m = mnew;                                                              \
    }

__global__ __launch_bounds__(256) void aggregate_kernel(const float* __restrict__ xl,
                                                        const float* __restrict__ xr,
                                                        const float* __restrict__ att,
                                                        const float* __restrict__ bias,
                                                        const int* __restrict__ off,
                                                        const int* __restrict__ esrc,
                                                        float* __restrict__ out,
                                                        ushort* __restrict__ hhi,
                                                        ushort* __restrict__ hlo,
                                                        int n, int do_relu) {
    int node = blockIdx.x * (blockDim.x >> 6) + (threadIdx.x >> 6);
    if (node >= n) return;
    const int lane = threadIdx.x & 63;

    const float2 xrv = ((const float2*)(xr + (size_t)node * HID))[lane];
    const float2 attv = ((const float2*)att)[lane];

    float m = -INFINITY, den = 0.f, acc0 = 0.f, acc1 = 0.f;
    const int start = off[node], end = off[node + 1];

    {   // self-loop (softmax order-invariant)
        float2 xlv = ((const float2*)(xl + (size_t)node * HID))[lane];
        PROC(xlv.x, xlv.y);
    }
    int j = start;
    for (; j + 3 < end; j += 4) {
        int s0 = esrc[j];
        int s1 = esrc[j + 1];
        int s2 = esrc[j + 2];
        int s3 = esrc[j + 3];
        float2 a = ((const float2*)(xl + (size_t)s0 * HID))[lane];
        float2 b = ((const float2*)(xl + (size_t)s1 * HID))[lane];
        float2 c = ((const float2*)(xl + (size_t)s2 * HID))[lane];
        float2 d = ((const float2*)(xl + (size_t)s3 * HID))[lane];
        PROC(a.x, a.y);
        PROC(b.x, b.y);
        PROC(c.x, c.y);
        PROC(d.x, d.y);
    }
    for (; j < end; ++j) {
        int s0 = esrc[j];
        float2 a = ((const float2*)(xl + (size_t)s0 * HID))[lane];
        PROC(a.x, a.y);
    }

    const float2 bv = ((const float2*)bias)[lane];
    float inv = 1.0f / den;
    float o0 = acc0 * inv + bv.x;
    float o1 = acc1 * inv + bv.y;
    if (do_relu) { o0 = fmaxf(o0, 0.f); o1 = fmaxf(o1, 0.f); }

    if (hhi) {
        ushort2 h, l;
        h.x = bf16_rne(o0); l.x = bf16_rne(o0 - bf16_tof(h.x));
        h.y = bf16_rne(o1); l.y = bf16_rne(o1 - bf16_tof(h.y));
        ((ushort2*)(hhi + (size_t)node * HID))[lane] = h;
        ((ushort2*)(hlo + (size_t)node * HID))[lane] = l;
    } else {
        ((float2*)(out + (size_t)node * HID))[lane] = make_float2(o0, o1);
    }
}

// ---------------- launch ----------------

extern "C" void kernel_launch(void* const* d_in, const int* in_sizes, int n_in,
                              void* d_out, int out_size, void* d_ws, size_t ws_size,
                              hipStream_t stream) {
    const float* x     = (const float*)d_in[0];
    const void*  edges = d_in[1];
    const float* Wl1   = (const float*)d_in[2];
    const float* Wr1   = (const float*)d_in[3];
    const float* att1  = (const float*)d_in[4];
    const float* b1    = (const float*)d_in[5];
    const float* Wl2   = (const float*)d_in[6];
    const float* Wr2   = (const float*)d_in[7];
    const float* att2  = (const float*)d_in[8];
    const float* b2    = (const float*)d_in[9];
    float* out = (float*)d_out;

    const int n = in_sizes[0] / HID;
    const int e = in_sizes[1] / 2;

    char* ws = (char*)d_ws;
    size_t o = 0;
    auto alloc = [&](size_t bytes) -> void* {
        void* p = ws + o;
        o = (o + bytes + 255) & ~(size_t)255;
        return p;
    };
    int* cnt      = (int*)alloc((size_t)n * 4);
    int* off      = (int*)alloc((size_t)(n + 1) * 4);
    int* cursor   = (int*)alloc((size_t)n * 4);
    int* esrc     = (int*)alloc((size_t)e * 4);
    int* tmp      = (int*)alloc((size_t)n * 4);
    int* partials = (int*)alloc(64 * 4);
    int* is64     = (int*)alloc(256);
    ushort* W1hi  = (ushort*)alloc(256 * 128 * 2);
    ushort* W1lo  = (ushort*)alloc(256 * 128 * 2);
    ushort* W2hi  = (ushort*)alloc(256 * 128 * 2);
    ushort* W2lo  = (ushort*)alloc(256 * 128 * 2);
    ushort* Xhi   = (ushort*)alloc((size_t)n * HID * 2);
    ushort* Xlo   = (ushort*)alloc((size_t)n * HID * 2);
    ushort* Hhi   = (ushort*)alloc((size_t)n * HID * 2);
    ushort* Hlo   = (ushort*)alloc((size_t)n * HID * 2);
    float* A      = (float*)alloc((size_t)n * HID * 4);   // xl
    float* B      = (float*)alloc((size_t)n * HID * 4);   // xr

    const int nchunks = (n + 1023) / 1024;   // 49 for n=50000 (<=64 required)
    const int gblocks = (n + 63) / 64;

    // CSR by destination (shared by both layers)
    detect64_kernel<<<1, 64, 0, stream>>>((const int*)edges, is64, 2LL * e);
    zero_cnt_kernel<<<(n + 255) / 256, 256, 0, stream>>>(cnt, n);
    hist_kernel<<<(e + 255) / 256, 256, 0, stream>>>(edges, is64, cnt, e);
    scan1_kernel<<<nchunks, 256, 0, stream>>>(cnt, tmp, partials, n);
    scan2_kernel<<<1, 64, 0, stream>>>(partials, nchunks, off + n);
    scan3_kernel<<<(n + 255) / 256, 256, 0, stream>>>(tmp, partials, off, cursor, n);
    scatter_kernel<<<(e + 255) / 256, 256, 0, stream>>>(edges, is64, cursor, esrc, e);

    // bf16 conversions
    convert_w_kernel<<<128, 256, 0, stream>>>(Wl1, Wr1, W1hi, W1lo);
    convert_w_kernel<<<128, 256, 0, stream>>>(Wl2, Wr2, W2hi, W2lo);
    const int total4 = n * HID / 4;
    convert_x_kernel<<<(total4 + 255) / 256, 256, 0, stream>>>(x, Xhi, Xlo, total4);

    // layer 1
    gemm_mfma_kernel<<<gblocks, 256, 0, stream>>>(Xhi, Xlo, W1hi, W1lo, A, B, n);
    aggregate_kernel<<<(n + 3) / 4, 256, 0, stream>>>(A, B, att1, b1, off, esrc,
                                                      (float*)nullptr, Hhi, Hlo, n, 1);

    // layer 2
    gemm_mfma_kernel<<<gblocks, 256, 0, stream>>>(Hhi, Hlo, W2hi, W2lo, A, B, n);
    aggregate_kernel<<<(n + 3) / 4, 256, 0, stream>>>(A, B, att2, b2, off, esrc,
                                                      out, (ushort*)nullptr, (ushort*)nullptr, n, 0);
}